// Round 13
// baseline (145.941 us; speedup 1.0000x reference)
//
#include <hip/hip_runtime.h>
#include <hip/hip_fp16.h>

typedef _Float16 half8 __attribute__((ext_vector_type(8)));
typedef float    floatx4 __attribute__((ext_vector_type(4)));
typedef unsigned int uintx4 __attribute__((ext_vector_type(4)));

#define MFMA16(a, b, c) __builtin_amdgcn_mfma_f32_16x16x32_f16((a), (b), (c), 0, 0, 0)

constexpr int T_ = 2048;
constexpr int D_ = 1024;
constexpr int NB = 4;
constexpr int NTILE = 136;               // lower-tri 128x128 P tiles per batch

__device__ __forceinline__ half8 cvt8(floatx4 a, floatx4 b) {
  half8 h;
  h[0] = (_Float16)a[0]; h[1] = (_Float16)a[1]; h[2] = (_Float16)a[2]; h[3] = (_Float16)a[3];
  h[4] = (_Float16)b[0]; h[5] = (_Float16)b[1]; h[6] = (_Float16)b[2]; h[7] = (_Float16)b[3];
  return h;
}

__device__ __forceinline__ void gl16(const void* g, void* l) {
  __builtin_amdgcn_global_load_lds(
      (const __attribute__((address_space(1))) void*)g,
      (__attribute__((address_space(3))) void*)l, 16, 0, 0);
}

__device__ __forceinline__ void STEP_SYNC() {
  asm volatile("s_waitcnt vmcnt(0) lgkmcnt(0)" ::: "memory");
  __builtin_amdgcn_s_barrier();
  __builtin_amdgcn_sched_barrier(0);
}

// ---- fused prep: Q f32->f16 cast (bid<2048) | VhT transpose build (else) ----
__global__ __launch_bounds__(256) void prep(const float* __restrict__ Q,
                                            const float* __restrict__ V,
                                            _Float16* __restrict__ Qh,
                                            _Float16* __restrict__ VhT) {
  __shared__ _Float16 tile[64][65];
  const int bid = blockIdx.x;
  if (bid < 2048) {
    const size_t i = ((size_t)bid * 256 + threadIdx.x) * 16;
    *(half8*)(Qh + i)     = cvt8(*(const floatx4*)(Q + i),     *(const floatx4*)(Q + i + 4));
    *(half8*)(Qh + i + 8) = cvt8(*(const floatx4*)(Q + i + 8), *(const floatx4*)(Q + i + 12));
    return;
  }
  const int b2 = bid - 2048;
  const int b = b2 & 3, tt = (b2 >> 2) & 31, dd = b2 >> 7;
  const float* Vb = V + ((size_t)b * T_ + tt * 64) * D_ + dd * 64;
#pragma unroll
  for (int k = 0; k < 16; ++k) {
    const int e = k * 256 + threadIdx.x, r = e >> 6, c = e & 63;
    tile[r][c] = (_Float16)Vb[(size_t)r * D_ + c];
  }
  __syncthreads();
#pragma unroll
  for (int k = 0; k < 16; ++k) {
    const int e = k * 256 + threadIdx.x, dr = e >> 6, tc = e & 63;
    VhT[((size_t)b * D_ + dd * 64 + dr) * T_ + tt * 64 + tc] = tile[tc][dr];
  }
}

// ---- S-GEMM + fused softmax partials: 256x128 C-tile, BK=64, dbuf issue-early ----
__global__ __launch_bounds__(512, 2) void sgemm(const _Float16* __restrict__ Qh,
                                                const float* __restrict__ V,
                                                _Float16* __restrict__ Pt,
                                                float* __restrict__ mg,
                                                float* __restrict__ lg) {
  extern __shared__ __align__(16) char lds[];  // [2] x ( A 32K f16 | B 32K f32 )
  const int tid = threadIdx.x;
  const int w = tid >> 6, l = tid & 63, l15 = l & 15, hi = l >> 4;
  const int wr = (w >> 1) * 64, wc = (w & 1) * 64;

  const int b = (int)(blockIdx.x & 3);
  int rem = (int)(blockIdx.x >> 2), j = 0;      // tiles (I,j), j <= 2I+1, j-major
  while (rem >= 8 - (j >> 1)) { rem -= 8 - (j >> 1); ++j; }
  const int I = (j >> 1) + rem;

  const _Float16* Qb = Qh + ((size_t)(b * T_ + I * 256)) * D_;
  const float*    Vb = V  + ((size_t)(b * T_ + j * 128)) * D_;

  const int arow = w * 32 + (l >> 3);           // + q*8 ; A: 256r x 64k f16
  const int brow = w * 16 + (l >> 4);           // + q*4 ; B: 128r x 64k f32

  auto STAGE = [&](const int s, const int buf) {
    char* Ad = lds + buf * 65536 + w * 4096;
    char* Bd = lds + buf * 65536 + 32768 + w * 4096;
#pragma unroll
    for (int q = 0; q < 4; ++q) {
      const int ar = arow + q * 8;
      gl16(Qb + (size_t)ar * D_ + s * 64 + ((l & 7) ^ (ar & 7)) * 8, Ad + q * 1024);
      const int br = brow + q * 4;
      gl16(Vb + (size_t)br * D_ + s * 64 + ((l & 15) ^ (br & 15)) * 4, Bd + q * 1024);
    }
  };

  floatx4 acc[4][4];
#pragma unroll
  for (int mi = 0; mi < 4; ++mi)
#pragma unroll
    for (int ni = 0; ni < 4; ++ni) acc[mi][ni] = (floatx4){0.f, 0.f, 0.f, 0.f};

  STAGE(0, 0);
  STEP_SYNC();
  for (int s = 0; s < 16; ++s) {
    const int cur = s & 1;
    const char* Ab = lds + cur * 65536;
    const char* Bb = lds + cur * 65536 + 32768;
    half8 af[4], bb[4];
    // s32 = 0 fragment reads
#pragma unroll
    for (int mi = 0; mi < 4; ++mi) {
      const int row = wr + mi * 16 + l15;
      af[mi] = *(const half8*)(Ab + row * 128 + ((hi ^ (row & 7)) << 4));
    }
#pragma unroll
    for (int ni = 0; ni < 4; ++ni) {
      const int row = wc + ni * 16 + l15;
      const int p = (hi * 2) ^ (row & 15);
      const floatx4 f0 = *(const floatx4*)(Bb + row * 256 + (p << 4));
      const floatx4 f1 = *(const floatx4*)(Bb + row * 256 + ((p << 4) ^ 16));
      bb[ni] = cvt8(f0, f1);
    }
    if (s + 1 < 16) STAGE(s + 1, cur ^ 1);      // in flight under both MFMA phases
#pragma unroll
    for (int mi = 0; mi < 4; ++mi)
#pragma unroll
      for (int ni = 0; ni < 4; ++ni)
        acc[mi][ni] = MFMA16(af[mi], bb[ni], acc[mi][ni]);
    // s32 = 1
#pragma unroll
    for (int mi = 0; mi < 4; ++mi) {
      const int row = wr + mi * 16 + l15;
      af[mi] = *(const half8*)(Ab + row * 128 + (((4 + hi) ^ (row & 7)) << 4));
    }
#pragma unroll
    for (int ni = 0; ni < 4; ++ni) {
      const int row = wc + ni * 16 + l15;
      const int p = (8 + hi * 2) ^ (row & 15);
      const floatx4 f0 = *(const floatx4*)(Bb + row * 256 + (p << 4));
      const floatx4 f1 = *(const floatx4*)(Bb + row * 256 + ((p << 4) ^ 16));
      bb[ni] = cvt8(f0, f1);
    }
#pragma unroll
    for (int mi = 0; mi < 4; ++mi)
#pragma unroll
      for (int ni = 0; ni < 4; ++ni)
        acc[mi][ni] = MFMA16(af[mi], bb[ni], acc[mi][ni]);
    STEP_SYNC();
  }

  // ---- fused epilogue: mask, per-tile row max/sum, P=exp(s-m) f16, dump ----
  float* Mex = (float*)lds;                      // [2][256]
  float* Lex = (float*)(lds + 2048);             // [2][256]
#pragma unroll
  for (int mi = 0; mi < 4; ++mi) {
    const int row0 = I * 256 + wr + mi * 16 + 4 * hi;
#pragma unroll
    for (int ni = 0; ni < 4; ++ni) {
      const int col = j * 128 + wc + ni * 16 + l15;
#pragma unroll
      for (int r = 0; r < 4; ++r)
        if (col > row0 + r) acc[mi][ni][r] = -1e30f;   // causal
    }
  }
  floatx4 mrow[4];
#pragma unroll
  for (int mi = 0; mi < 4; ++mi) {
#pragma unroll
    for (int r = 0; r < 4; ++r)
      mrow[mi][r] = fmaxf(fmaxf(acc[mi][0][r], acc[mi][1][r]),
                          fmaxf(acc[mi][2][r], acc[mi][3][r]));
#pragma unroll
    for (int off = 1; off < 16; off <<= 1)
#pragma unroll
      for (int r = 0; r < 4; ++r)
        mrow[mi][r] = fmaxf(mrow[mi][r], __shfl_xor(mrow[mi][r], off));
  }
  if (l15 == 0) {
#pragma unroll
    for (int mi = 0; mi < 4; ++mi)
      *(floatx4*)&Mex[(w & 1) * 256 + wr + mi * 16 + 4 * hi] = mrow[mi];
  }
  __syncthreads();
#pragma unroll
  for (int mi = 0; mi < 4; ++mi) {
    const int r0 = wr + mi * 16 + 4 * hi;
    const floatx4 m0 = *(const floatx4*)&Mex[r0];
    const floatx4 m1 = *(const floatx4*)&Mex[256 + r0];
#pragma unroll
    for (int r = 0; r < 4; ++r) mrow[mi][r] = fmaxf(m0[r], m1[r]);
  }
  char* Pw = (w >> 2) ? (lds + 98304) : (lds + 65536);   // P-half scratch (32K each)
  floatx4 ls[4];
#pragma unroll
  for (int mi = 0; mi < 4; ++mi) {
    ls[mi] = (floatx4){0.f, 0.f, 0.f, 0.f};
    const int rl = (wr & 127) + mi * 16 + 4 * hi;
#pragma unroll
    for (int ni = 0; ni < 4; ++ni) {
      const int col = wc + ni * 16 + l15;
#pragma unroll
      for (int r = 0; r < 4; ++r) {
        const float p = __expf(acc[mi][ni][r] - mrow[mi][r]);
        ls[mi][r] += p;
        *(_Float16*)(Pw + (rl + r) * 256 + col * 2) = (_Float16)p;
      }
    }
#pragma unroll
    for (int off = 1; off < 16; off <<= 1)
#pragma unroll
      for (int r = 0; r < 4; ++r) ls[mi][r] += __shfl_xor(ls[mi][r], off);
  }
  if (l15 == 0) {
#pragma unroll
    for (int mi = 0; mi < 4; ++mi)
      *(floatx4*)&Lex[(w & 1) * 256 + wr + mi * 16 + 4 * hi] = ls[mi];
  }
  __syncthreads();

  if (((w & 1) == 0) && l15 == 0) {              // m/l sidecar, guarded
    const size_t base = ((size_t)(b * 16 + j)) * 2048;
#pragma unroll
    for (int mi = 0; mi < 4; ++mi) {
      const int r0 = wr + mi * 16 + 4 * hi;
      const int gr = I * 256 + r0;
      if (gr >= j * 128) {
#pragma unroll
        for (int r = 0; r < 4; ++r) {
          mg[base + gr + r] = mrow[mi][r];
          lg[base + gr + r] = Lex[r0 + r] + Lex[256 + r0 + r];
        }
      }
    }
  }
  {                                               // P tile dump (both halves)
    const int th = tid >> 8, tt = tid & 255;
    const int it = 2 * I + th;
    if (j <= it) {
      char* Pg = (char*)(Pt + ((size_t)(b * NTILE + ((it * (it + 1)) >> 1) + j)) * 16384);
      const char* src = th ? (lds + 98304) : (lds + 65536);
      const int drow = tt >> 1, dh = tt & 1;
#pragma unroll
      for (int k = 0; k < 8; ++k) {
        const int c = k ^ (tt & 7);
        *(uintx4*)(Pg + drow * 256 + dh * 128 + c * 16) =
            *(const uintx4*)(src + drow * 256 + dh * 128 + c * 16);
      }
    }
  }
}

// ---- combine: per row, M = max m_j, alpha_j = exp(m_j - M), linv = 1/sum ----
__global__ __launch_bounds__(256) void combine(const float* __restrict__ mg,
                                               const float* __restrict__ lg,
                                               _Float16* __restrict__ ah,
                                               float* __restrict__ linv) {
  const int gid = (int)(blockIdx.x * 256 + threadIdx.x);   // 8192
  const int b = gid >> 11, row = gid & 2047, i = row >> 7;
  const size_t mb = (size_t)b * 32768 + row;               // m[b][j][row]
  float M = -1e30f;
  for (int j = 0; j <= i; ++j) M = fmaxf(M, mg[mb + (size_t)j * 2048]);
  float L = 0.f;
  for (int j = 0; j <= i; ++j) {
    const float a = __expf(mg[mb + (size_t)j * 2048] - M);
    L += a * lg[mb + (size_t)j * 2048];
    ah[((size_t)b * 2048 + row) * 16 + j] = (_Float16)a;
  }
  linv[b * 2048 + row] = 1.0f / L;
}

// ---- PV: 256x64 C-tile, BK=64, dbuf issue-early, zero-fill missing P half ----
__global__ __launch_bounds__(512, 4) void pv(const _Float16* __restrict__ Pt,
                                             const _Float16* __restrict__ VhT,
                                             const _Float16* __restrict__ ah,
                                             const float* __restrict__ linv,
                                             float* __restrict__ O) {
  extern __shared__ __align__(16) char lds[];  // [2] x ( A 32K | B 8K ) = 80K
  const int tid = threadIdx.x;
  const int w = tid >> 6, l = tid & 63, l15 = l & 15, hi = l >> 4;
  const int wr = (w >> 1) * 64, wc = (w & 1) * 32;

  const int b = (int)(blockIdx.x & 3);
  const int u = (int)(blockIdx.x >> 2);        // 0..127
  const int r_ = u >> 4;
  const int I = (r_ < 4) ? (7 - r_) : (r_ - 4);  // bid and bid+256 pair: sum const
  const int nc = u & 15;
  const int ns = 4 * I + 4;

  const int h = w >> 2;                        // A-row half owned by this wave
  const int it = 2 * I + h;
  const int arow = w * 32 + (l >> 3);          // + q*8 ; A rows 0..255
  const int vrow = w * 8 + (l >> 3);           // B rows 0..63

  auto STAGE = [&](const int s, const int buf) {
    char* Ad = lds + buf * 40960 + w * 4096;
    char* Bd = lds + buf * 40960 + 32768 + w * 1024;
    const int jt = s >> 1;
    if (jt <= it) {
      const _Float16* Pb = Pt + ((size_t)(b * NTILE + ((it * (it + 1)) >> 1) + jt)) * 16384;
#pragma unroll
      for (int q = 0; q < 4; ++q) {
        const int ar = arow + q * 8;
        gl16(Pb + (size_t)(ar & 127) * 128 + (s & 1) * 64 + ((l & 7) ^ (ar & 7)) * 8,
             Ad + q * 1024);
      }
    } else {                                   // tile above diagonal: zeros
#pragma unroll
      for (int q = 0; q < 4; ++q)
        *(uintx4*)(Ad + q * 1024 + l * 16) = (uintx4){0u, 0u, 0u, 0u};
    }
    gl16(VhT + ((size_t)(b * D_ + nc * 64 + vrow)) * T_ + s * 64 + ((l & 7) ^ (vrow & 7)) * 8,
         Bd);
  };

  floatx4 acc[4][2];
#pragma unroll
  for (int mi = 0; mi < 4; ++mi)
#pragma unroll
    for (int ni = 0; ni < 2; ++ni) acc[mi][ni] = (floatx4){0.f, 0.f, 0.f, 0.f};

  STAGE(0, 0);
  STEP_SYNC();
  for (int s = 0; s < ns; ++s) {
    const int cur = s & 1;
    const char* Ab = lds + cur * 40960;
    const char* Bb = lds + cur * 40960 + 32768;
    const int jt = s >> 1;
    _Float16 aw[4];
#pragma unroll
    for (int mi = 0; mi < 4; ++mi)
      aw[mi] = ah[((size_t)(b * T_ + I * 256 + wr + mi * 16 + l15)) * 16 + jt];
    half8 af[4], bb[2];
#pragma unroll
    for (int mi = 0; mi < 4; ++mi) {
      const int row = wr + mi * 16 + l15;
      af[mi] = *(const half8*)(Ab + row * 128 + ((hi ^ (row & 7)) << 4));
      af[mi] *= aw[mi];
    }
#pragma unroll
    for (int ni = 0; ni < 2; ++ni) {
      const int row = wc + ni * 16 + l15;
      bb[ni] = *(const half8*)(Bb + row * 128 + ((hi ^ (row & 7)) << 4));
    }
    if (s + 1 < ns) STAGE(s + 1, cur ^ 1);
#pragma unroll
    for (int mi = 0; mi < 4; ++mi)
#pragma unroll
      for (int ni = 0; ni < 2; ++ni)
        acc[mi][ni] = MFMA16(af[mi], bb[ni], acc[mi][ni]);
#pragma unroll
    for (int mi = 0; mi < 4; ++mi) {
      const int row = wr + mi * 16 + l15;
      af[mi] = *(const half8*)(Ab + row * 128 + (((4 + hi) ^ (row & 7)) << 4));
      af[mi] *= aw[mi];
    }
#pragma unroll
    for (int ni = 0; ni < 2; ++ni) {
      const int row = wc + ni * 16 + l15;
      bb[ni] = *(const half8*)(Bb + row * 128 + (((4 + hi) ^ (row & 7)) << 4));
    }
#pragma unroll
    for (int mi = 0; mi < 4; ++mi)
#pragma unroll
      for (int ni = 0; ni < 2; ++ni)
        acc[mi][ni] = MFMA16(af[mi], bb[ni], acc[mi][ni]);
    STEP_SYNC();
  }

  float* Ob = O + ((size_t)(b * T_ + I * 256)) * D_ + nc * 64;
#pragma unroll
  for (int mi = 0; mi < 4; ++mi)
#pragma unroll
    for (int r = 0; r < 4; ++r) {
      const int rl = wr + mi * 16 + 4 * hi + r;
      const float iv = linv[b * T_ + I * 256 + rl];
#pragma unroll
      for (int ni = 0; ni < 2; ++ni)
        Ob[(size_t)rl * D_ + wc + ni * 16 + l15] = acc[mi][ni][r] * iv;
    }
}

// ---- fallback (ws too small — slow but correct) ----
__global__ __launch_bounds__(256) void attn_fb(const float* __restrict__ Q,
                                               const float* __restrict__ V,
                                               float* __restrict__ O) {
  __shared__ float sc[2048];
  __shared__ float red[4];
  const int b = (int)(blockIdx.x >> 11), m = (int)(blockIdx.x & 2047);
  const int tid = threadIdx.x;
  const float* Qr = Q + ((size_t)b * T_ + m) * D_;
  for (int kv = tid; kv <= m; kv += 256) {
    const float* Vr = V + ((size_t)b * T_ + kv) * D_;
    float s = 0.f;
    for (int d = 0; d < D_; d += 4) {
      floatx4 q4 = *(const floatx4*)(Qr + d), v4 = *(const floatx4*)(Vr + d);
      s += q4[0] * v4[0] + q4[1] * v4[1] + q4[2] * v4[2] + q4[3] * v4[3];
    }
    sc[kv] = s;
  }
  __syncthreads();
  float mx = -1e30f;
  for (int kv = tid; kv <= m; kv += 256) mx = fmaxf(mx, sc[kv]);
#pragma unroll
  for (int off = 1; off < 64; off <<= 1) mx = fmaxf(mx, __shfl_xor(mx, off));
  if ((tid & 63) == 0) red[tid >> 6] = mx;
  __syncthreads();
  mx = fmaxf(fmaxf(red[0], red[1]), fmaxf(red[2], red[3]));
  __syncthreads();
  float sum = 0.f;
  for (int kv = tid; kv <= m; kv += 256) { float p = __expf(sc[kv] - mx); sc[kv] = p; sum += p; }
#pragma unroll
  for (int off = 1; off < 64; off <<= 1) sum += __shfl_xor(sum, off);
  __syncthreads();
  if ((tid & 63) == 0) red[tid >> 6] = sum;
  __syncthreads();
  const float inv = 1.0f / (red[0] + red[1] + red[2] + red[3]);
  float* Or = O + ((size_t)b * T_ + m) * D_;
  const int d = tid * 4;
  floatx4 o = {0.f, 0.f, 0.f, 0.f};
  for (int kv = 0; kv <= m; ++kv) {
    const float p = sc[kv];
    const floatx4 v4 = *(const floatx4*)(V + ((size_t)b * T_ + kv) * D_ + d);
    o[0] += p * v4[0]; o[1] += p * v4[1]; o[2] += p * v4[2]; o[3] += p * v4[3];
  }
  o[0] *= inv; o[1] *= inv; o[2] *= inv; o[3] *= inv;
  *(floatx4*)(Or + d) = o;
}

extern "C" void kernel_launch(void* const* d_in, const int* in_sizes, int n_in,
                              void* d_out, int out_size, void* d_ws, size_t ws_size,
                              hipStream_t stream) {
  const float* q = (const float*)d_in[0];
  const float* v = (const float*)d_in[1];
  float* out = (float*)d_out;

  const size_t OFF_VT = 16777216;                 // Qh @0
  const size_t OFF_P  = 33554432;
  const size_t OFF_M  = OFF_P + (size_t)NB * NTILE * 16384 * 2;  // 51,380,224
  const size_t OFF_LG = OFF_M + 524288;
  const size_t OFF_AH = OFF_LG + 524288;
  const size_t OFF_LI = OFF_AH + 262144;
  const size_t NEED   = OFF_LI + 32768;           // ~52.7 MB

  if (ws_size >= NEED) {
    _Float16* qh = (_Float16*)d_ws;
    _Float16* vt = (_Float16*)((char*)d_ws + OFF_VT);
    _Float16* pt = (_Float16*)((char*)d_ws + OFF_P);
    float* mg = (float*)((char*)d_ws + OFF_M);
    float* lg = (float*)((char*)d_ws + OFF_LG);
    _Float16* ah = (_Float16*)((char*)d_ws + OFF_AH);
    float* li = (float*)((char*)d_ws + OFF_LI);
    hipFuncSetAttribute((const void*)sgemm, hipFuncAttributeMaxDynamicSharedMemorySize, 131072);
    hipFuncSetAttribute((const void*)pv, hipFuncAttributeMaxDynamicSharedMemorySize, 81920);
    prep<<<dim3(4096), dim3(256), 0, stream>>>(q, v, qh, vt);
    sgemm<<<dim3(NB * 72), dim3(512), 131072, stream>>>(qh, v, pt, mg, lg);
    combine<<<dim3(32), dim3(256), 0, stream>>>(mg, lg, ah, li);
    pv<<<dim3(512), dim3(512), 81920, stream>>>(pt, vt, ah, li, out);
  } else {
    attn_fb<<<dim3(NB * T_), dim3(256), 0, stream>>>(q, v, out);
  }
}

// Round 14
// 120.718 us; speedup vs baseline: 1.2089x; 1.2089x over previous
//
#include <hip/hip_runtime.h>
#include <hip/hip_fp16.h>

typedef _Float16 half8 __attribute__((ext_vector_type(8)));
typedef float    floatx4 __attribute__((ext_vector_type(4)));
typedef unsigned int uintx4 __attribute__((ext_vector_type(4)));

#define MFMA16(a, b, c) __builtin_amdgcn_mfma_f32_16x16x32_f16((a), (b), (c), 0, 0, 0)

constexpr int T_ = 2048;
constexpr int D_ = 1024;
constexpr int NB = 4;
constexpr int NTILE = 136;               // lower-tri 128x128 tiles per batch
constexpr size_t PT_ELEMS = 16384;       // P tile: 128x128 f16

__device__ __forceinline__ half8 cvt8(floatx4 a, floatx4 b) {
  half8 h;
  h[0] = (_Float16)a[0]; h[1] = (_Float16)a[1]; h[2] = (_Float16)a[2]; h[3] = (_Float16)a[3];
  h[4] = (_Float16)b[0]; h[5] = (_Float16)b[1]; h[6] = (_Float16)b[2]; h[7] = (_Float16)b[3];
  return h;
}

__device__ __forceinline__ void gl16(const void* g, void* l) {
  __builtin_amdgcn_global_load_lds(
      (const __attribute__((address_space(1))) void*)g,
      (__attribute__((address_space(3))) void*)l, 16, 0, 0);
}

// ---- fused prep: Q f32->f16 (bid<2048) | V f32->f16 (else), 16 elems/thread ----
__global__ __launch_bounds__(256) void prep(const float* __restrict__ Q,
                                            const float* __restrict__ V,
                                            _Float16* __restrict__ Qh,
                                            _Float16* __restrict__ Vh) {
  const int bid = blockIdx.x;
  const float* src = (bid < 2048) ? Q : V;
  _Float16* dst = (bid < 2048) ? Qh : Vh;
  const size_t i = ((size_t)(bid & 2047) * 256 + threadIdx.x) * 16;
  *(half8*)(dst + i)     = cvt8(*(const floatx4*)(src + i),     *(const floatx4*)(src + i + 4));
  *(half8*)(dst + i + 8) = cvt8(*(const floatx4*)(src + i + 8), *(const floatx4*)(src + i + 12));
}

// ---- prep: VhT[b][d][t] f16 plain transpose (runs after sgemm, into Qh slot) ----
__global__ __launch_bounds__(256) void build_vt(const float* __restrict__ V,
                                                _Float16* __restrict__ VhT) {
  __shared__ _Float16 tile[64][65];
  const int bid = blockIdx.x;
  const int b = bid & 3, tt = (bid >> 2) & 31, dd = bid >> 7;
  const float* Vb = V + ((size_t)b * T_ + tt * 64) * D_ + dd * 64;
#pragma unroll
  for (int k = 0; k < 16; ++k) {
    const int e = k * 256 + threadIdx.x, r = e >> 6, c = e & 63;
    tile[r][c] = (_Float16)Vb[(size_t)r * D_ + c];
  }
  __syncthreads();
#pragma unroll
  for (int k = 0; k < 16; ++k) {
    const int e = k * 256 + threadIdx.x, dr = e >> 6, tc = e & 63;
    VhT[((size_t)b * D_ + dd * 64 + dr) * T_ + tt * 64 + tc] = tile[tc][dr];
  }
}

// ---- S-GEMM + fused per-tile softmax partials (VERBATIM r12, proven 44.7us) ----
__global__ __launch_bounds__(256, 2) void sgemm(const _Float16* __restrict__ Qh,
                                                const _Float16* __restrict__ Vh,
                                                _Float16* __restrict__ Pt,
                                                float* __restrict__ mg,
                                                float* __restrict__ lg) {
  extern __shared__ __align__(16) char lds[];   // As 32K | Bs 32K
  char* As = lds;
  char* Bs = lds + 32768;
  const int tid = threadIdx.x;
  const int w = tid >> 6, l = tid & 63, l15 = l & 15, hi = l >> 4;
  const int wr = (w >> 1) * 64, wc = (w & 1) * 64;

  const int b = (int)(blockIdx.x & 3);
  int rem = (int)(blockIdx.x >> 2), j = 0;      // j-major (B-panel L2 reuse)
  while (rem >= 16 - j) { rem -= 16 - j; ++j; }
  const int i = j + rem;

  const _Float16* Qb = Qh + ((size_t)(b * T_ + i * 128)) * D_;
  const _Float16* Vb = Vh + ((size_t)(b * T_ + j * 128)) * D_;
  const int srow = w * 32 + (l >> 4);
  char* Adst = As + w * 8192;
  char* Bdst = Bs + w * 8192;

  floatx4 acc[4][4];
#pragma unroll
  for (int mi = 0; mi < 4; ++mi)
#pragma unroll
    for (int ni = 0; ni < 4; ++ni) acc[mi][ni] = (floatx4){0.f, 0.f, 0.f, 0.f};

  for (int s = 0; s < 8; ++s) {
#pragma unroll
    for (int q = 0; q < 8; ++q) {
      const int r0 = srow + q * 4;
      const int sc = ((l & 15) ^ (r0 & 15)) * 8;
      gl16(Qb + (size_t)r0 * D_ + s * 128 + sc, Adst + q * 1024);
      gl16(Vb + (size_t)r0 * D_ + s * 128 + sc, Bdst + q * 1024);
    }
    __syncthreads();
#pragma unroll
    for (int s32 = 0; s32 < 4; ++s32) {
      half8 af[4], bb[4];
#pragma unroll
      for (int mi = 0; mi < 4; ++mi) {
        const int row = wr + mi * 16 + l15;
        af[mi] = *(const half8*)(As + row * 256 + (((s32 * 4 + hi) ^ (row & 15)) << 4));
      }
#pragma unroll
      for (int ni = 0; ni < 4; ++ni) {
        const int row = wc + ni * 16 + l15;
        bb[ni] = *(const half8*)(Bs + row * 256 + (((s32 * 4 + hi) ^ (row & 15)) << 4));
      }
#pragma unroll
      for (int mi = 0; mi < 4; ++mi)
#pragma unroll
        for (int ni = 0; ni < 4; ++ni)
          acc[mi][ni] = MFMA16(af[mi], bb[ni], acc[mi][ni]);
    }
    __syncthreads();
  }

  float* Mex = (float*)Bs;                      // [2][128]
  float* Lex = (float*)(Bs + 1024);             // [2][128]

  if (i == j) {
#pragma unroll
    for (int mi = 0; mi < 4; ++mi)
#pragma unroll
      for (int ni = 0; ni < 4; ++ni) {
        const int col = wc + ni * 16 + l15;
        const int row0 = wr + mi * 16 + 4 * hi;
#pragma unroll
        for (int r = 0; r < 4; ++r)
          if (col > row0 + r) acc[mi][ni][r] = -1e30f;
      }
  }

  floatx4 mrow[4];
#pragma unroll
  for (int mi = 0; mi < 4; ++mi) {
#pragma unroll
    for (int r = 0; r < 4; ++r)
      mrow[mi][r] = fmaxf(fmaxf(acc[mi][0][r], acc[mi][1][r]),
                          fmaxf(acc[mi][2][r], acc[mi][3][r]));
#pragma unroll
    for (int off = 1; off < 16; off <<= 1)
#pragma unroll
      for (int r = 0; r < 4; ++r)
        mrow[mi][r] = fmaxf(mrow[mi][r], __shfl_xor(mrow[mi][r], off));
  }
  if (l15 == 0) {
#pragma unroll
    for (int mi = 0; mi < 4; ++mi)
      *(floatx4*)&Mex[(w & 1) * 128 + wr + mi * 16 + 4 * hi] = mrow[mi];
  }
  __syncthreads();
#pragma unroll
  for (int mi = 0; mi < 4; ++mi) {
    const floatx4 m0 = *(const floatx4*)&Mex[wr + mi * 16 + 4 * hi];
    const floatx4 m1 = *(const floatx4*)&Mex[128 + wr + mi * 16 + 4 * hi];
#pragma unroll
    for (int r = 0; r < 4; ++r) mrow[mi][r] = fmaxf(m0[r], m1[r]);
  }

  floatx4 lsum[4];
#pragma unroll
  for (int mi = 0; mi < 4; ++mi) {
    lsum[mi] = (floatx4){0.f, 0.f, 0.f, 0.f};
    const int row0 = wr + mi * 16 + 4 * hi;
#pragma unroll
    for (int ni = 0; ni < 4; ++ni) {
      const int col = wc + ni * 16 + l15;
#pragma unroll
      for (int r = 0; r < 4; ++r) {
        const float p = __expf(acc[mi][ni][r] - mrow[mi][r]);
        lsum[mi][r] += p;
        *(_Float16*)(As + (row0 + r) * 256 + col * 2) = (_Float16)p;
      }
    }
#pragma unroll
    for (int off = 1; off < 16; off <<= 1)
#pragma unroll
      for (int r = 0; r < 4; ++r) lsum[mi][r] += __shfl_xor(lsum[mi][r], off);
  }
  if (l15 == 0) {
#pragma unroll
    for (int mi = 0; mi < 4; ++mi)
      *(floatx4*)&Lex[(w & 1) * 128 + wr + mi * 16 + 4 * hi] = lsum[mi];
  }
  __syncthreads();

  if (((w & 1) == 0) && l15 == 0) {
    const size_t base = ((size_t)(b * 16 + j)) * 2048 + i * 128;
#pragma unroll
    for (int mi = 0; mi < 4; ++mi) {
      const int r0 = wr + mi * 16 + 4 * hi;
      const floatx4 l0 = *(const floatx4*)&Lex[r0];
      const floatx4 l1 = *(const floatx4*)&Lex[128 + r0];
#pragma unroll
      for (int r = 0; r < 4; ++r) {
        mg[base + r0 + r] = mrow[mi][r];
        lg[base + r0 + r] = l0[r] + l1[r];
      }
    }
  }
  _Float16* Pg = Pt + (size_t)(b * NTILE + ((i * (i + 1)) >> 1) + j) * PT_ELEMS;
  const int drow = tid >> 1, dhalf = tid & 1;
#pragma unroll
  for (int k = 0; k < 8; ++k) {
    const int c = k ^ (tid & 7);
    const uintx4 v = *(const uintx4*)(As + drow * 256 + dhalf * 128 + c * 16);
    *(uintx4*)((char*)Pg + drow * 256 + dhalf * 128 + c * 16) = v;
  }
}

// ---- combine: per row, M = max m_j, alpha_j = exp(m_j - M), linv = 1/sum ----
__global__ __launch_bounds__(256) void combine(const float* __restrict__ mg,
                                               const float* __restrict__ lg,
                                               _Float16* __restrict__ ah,
                                               float* __restrict__ linv) {
  const int gid = (int)(blockIdx.x * 256 + threadIdx.x);   // 8192
  const int b = gid >> 11, row = gid & 2047, i = row >> 7;
  const size_t mb = (size_t)b * 32768 + row;               // m[b][j][row]
  float M = -1e30f;
  for (int j = 0; j <= i; ++j) M = fmaxf(M, mg[mb + (size_t)j * 2048]);
  float L = 0.f;
  for (int j = 0; j <= i; ++j) {
    const float a = __expf(mg[mb + (size_t)j * 2048] - M);
    L += a * lg[mb + (size_t)j * 2048];
    ah[((size_t)b * 2048 + row) * 16 + j] = (_Float16)a;
  }
  linv[b * 2048 + row] = 1.0f / L;
}

// ---- PV: 128x64 C-tile, BK=64, single-buf gl16, 1024 blocks (4/CU TLP) ----
__global__ __launch_bounds__(256, 4) void pv(const _Float16* __restrict__ Pt,
                                             const _Float16* __restrict__ VhT,
                                             const _Float16* __restrict__ ah,
                                             const float* __restrict__ linv,
                                             float* __restrict__ O) {
  __shared__ __align__(16) char As[16384];   // P [128 q][64 kv] f16
  __shared__ __align__(16) char Bs[8192];    // VhT [64 d][64 kv] f16
  const int tid = threadIdx.x;
  const int w = tid >> 6, l = tid & 63, l15 = l & 15, hi = l >> 4;
  const int wr = w * 32;                     // wave's 32 q-rows

  const int b = (int)(blockIdx.x & 3);
  const int u = (int)(blockIdx.x >> 2);      // 0..255
  const int iidx = (u + (u >> 4)) & 15;      // mix i across CU residency
  const int i = (iidx < 8) ? (15 - iidx) : (iidx - 8);
  const int nc = u >> 4;                     // 0..15, 64-wide D slice
  const int ns = (i + 1) * 2;

  const _Float16* Pp = Pt + (size_t)(b * NTILE + ((i * (i + 1)) >> 1)) * PT_ELEMS;
  const _Float16* Vt = VhT + ((size_t)(b * D_ + nc * 64)) * T_;

  floatx4 acc[2][4];
#pragma unroll
  for (int mi = 0; mi < 2; ++mi)
#pragma unroll
    for (int ni = 0; ni < 4; ++ni) acc[mi][ni] = (floatx4){0.f, 0.f, 0.f, 0.f};

  for (int s = 0; s < ns; ++s) {
    const int jt = s >> 1, half = s & 1;
    _Float16 aw[2];
#pragma unroll
    for (int mi = 0; mi < 2; ++mi)
      aw[mi] = ah[((size_t)(b * 2048 + i * 128 + wr + mi * 16 + l15)) * 16 + jt];
#pragma unroll
    for (int q = 0; q < 4; ++q) {            // A: 128 rows x 64 kv
      const int ar = w * 32 + q * 8 + (l >> 3);
      gl16(Pp + (size_t)jt * PT_ELEMS + (size_t)ar * 128 + half * 64 +
               ((l & 7) ^ (ar & 7)) * 8,
           As + w * 4096 + q * 1024);
    }
#pragma unroll
    for (int q = 0; q < 2; ++q) {            // B: 64 rows x 64 kv
      const int br = w * 16 + q * 8 + (l >> 3);
      gl16(Vt + (size_t)br * T_ + s * 64 + ((l & 7) ^ (br & 7)) * 8,
           Bs + w * 2048 + q * 1024);
    }
    __syncthreads();                         // drains gl16 + aw loads
#pragma unroll
    for (int s32 = 0; s32 < 2; ++s32) {
      half8 af[2], bb[4];
#pragma unroll
      for (int mi = 0; mi < 2; ++mi) {
        const int row = wr + mi * 16 + l15;
        af[mi] = *(const half8*)(As + row * 128 + (((s32 * 4 + hi) ^ (row & 7)) << 4));
        af[mi] *= aw[mi];                    // flash rescale
      }
#pragma unroll
      for (int ni = 0; ni < 4; ++ni) {
        const int row = ni * 16 + l15;
        bb[ni] = *(const half8*)(Bs + row * 128 + (((s32 * 4 + hi) ^ (row & 7)) << 4));
      }
#pragma unroll
      for (int mi = 0; mi < 2; ++mi)
#pragma unroll
        for (int ni = 0; ni < 4; ++ni)
          acc[mi][ni] = MFMA16(af[mi], bb[ni], acc[mi][ni]);
    }
    __syncthreads();
  }

  float* Ob = O + ((size_t)b * T_ + i * 128) * D_ + nc * 64;
#pragma unroll
  for (int mi = 0; mi < 2; ++mi)
#pragma unroll
    for (int r = 0; r < 4; ++r) {
      const int rl = wr + mi * 16 + 4 * hi + r;
      const float iv = linv[b * 2048 + i * 128 + rl];
#pragma unroll
      for (int ni = 0; ni < 4; ++ni)
        Ob[(size_t)rl * D_ + ni * 16 + l15] = acc[mi][ni][r] * iv;
    }
}

// ---- fallback (ws too small — slow but correct) ----
__global__ __launch_bounds__(256) void attn_fb(const float* __restrict__ Q,
                                               const float* __restrict__ V,
                                               float* __restrict__ O) {
  __shared__ float sc[2048];
  __shared__ float red[4];
  const int b = (int)(blockIdx.x >> 11), m = (int)(blockIdx.x & 2047);
  const int tid = threadIdx.x;
  const float* Qr = Q + ((size_t)b * T_ + m) * D_;
  for (int kv = tid; kv <= m; kv += 256) {
    const float* Vr = V + ((size_t)b * T_ + kv) * D_;
    float s = 0.f;
    for (int d = 0; d < D_; d += 4) {
      floatx4 q4 = *(const floatx4*)(Qr + d), v4 = *(const floatx4*)(Vr + d);
      s += q4[0] * v4[0] + q4[1] * v4[1] + q4[2] * v4[2] + q4[3] * v4[3];
    }
    sc[kv] = s;
  }
  __syncthreads();
  float mx = -1e30f;
  for (int kv = tid; kv <= m; kv += 256) mx = fmaxf(mx, sc[kv]);
#pragma unroll
  for (int off = 1; off < 64; off <<= 1) mx = fmaxf(mx, __shfl_xor(mx, off));
  if ((tid & 63) == 0) red[tid >> 6] = mx;
  __syncthreads();
  mx = fmaxf(fmaxf(red[0], red[1]), fmaxf(red[2], red[3]));
  __syncthreads();
  float sum = 0.f;
  for (int kv = tid; kv <= m; kv += 256) { float p = __expf(sc[kv] - mx); sc[kv] = p; sum += p; }
#pragma unroll
  for (int off = 1; off < 64; off <<= 1) sum += __shfl_xor(sum, off);
  __syncthreads();
  if ((tid & 63) == 0) red[tid >> 6] = sum;
  __syncthreads();
  const float inv = 1.0f / (red[0] + red[1] + red[2] + red[3]);
  float* Or = O + ((size_t)b * T_ + m) * D_;
  const int d = tid * 4;
  floatx4 o = {0.f, 0.f, 0.f, 0.f};
  for (int kv = 0; kv <= m; ++kv) {
    const float p = sc[kv];
    const floatx4 v4 = *(const floatx4*)(V + ((size_t)b * T_ + kv) * D_ + d);
    o[0] += p * v4[0]; o[1] += p * v4[1]; o[2] += p * v4[2]; o[3] += p * v4[3];
  }
  o[0] *= inv; o[1] *= inv; o[2] *= inv; o[3] *= inv;
  *(floatx4*)(Or + d) = o;
}

extern "C" void kernel_launch(void* const* d_in, const int* in_sizes, int n_in,
                              void* d_out, int out_size, void* d_ws, size_t ws_size,
                              hipStream_t stream) {
  const float* q = (const float*)d_in[0];
  const float* v = (const float*)d_in[1];
  float* out = (float*)d_out;

  const size_t OFF_VH = 16777216;                       // Qh @0 (reused as VhT)
  const size_t OFF_P  = 33554432;
  const size_t OFF_M  = OFF_P + (size_t)NB * NTILE * PT_ELEMS * 2;  // 51,380,224
  const size_t OFF_LT = OFF_M + 524288;
  const size_t OFF_AH = OFF_LT + 524288;
  const size_t OFF_LI = OFF_AH + 262144;
  const size_t NEED   = OFF_LI + 32768;                 // ~52.7 MB (< proven 67.2)

  if (ws_size >= NEED) {
    _Float16* qh = (_Float16*)d_ws;                     // later VhT
    _Float16* vh = (_Float16*)((char*)d_ws + OFF_VH);
    _Float16* pt = (_Float16*)((char*)d_ws + OFF_P);
    float* mg = (float*)((char*)d_ws + OFF_M);
    float* lg = (float*)((char*)d_ws + OFF_LT);
    _Float16* ah = (_Float16*)((char*)d_ws + OFF_AH);
    float* li = (float*)((char*)d_ws + OFF_LI);
    hipFuncSetAttribute((const void*)sgemm, hipFuncAttributeMaxDynamicSharedMemorySize, 65536);
    prep<<<dim3(4096), dim3(256), 0, stream>>>(q, v, qh, vh);
    sgemm<<<dim3(NB * NTILE), dim3(256), 65536, stream>>>(qh, vh, pt, mg, lg);
    combine<<<dim3(32), dim3(256), 0, stream>>>(mg, lg, ah, li);
    build_vt<<<dim3(2048), dim3(256), 0, stream>>>(v, qh);   // Qh dead -> VhT
    pv<<<dim3(1024), dim3(256), 0, stream>>>(pt, qh, ah, li, out);
  } else {
    attn_fb<<<dim3(NB * T_), dim3(256), 0, stream>>>(q, v, out);
  }
}